// Round 6
// baseline (471.536 us; speedup 1.0000x reference)
//
#include <hip/hip_runtime.h>
#include <math.h>

#define B_   32
#define C_   64
#define T_   12
#define NV   883
#define TTW  10          // T-2 output time steps
#define K3   2649        // 3*NV
#define KSEG 28          // k-tiles per 883-segment (28*32=896, zero-padded)

typedef __attribute__((ext_vector_type(8))) short bf16x8;   // 8 bf16 = 4 VGPRs (MFMA A/B frag)
typedef __attribute__((ext_vector_type(4))) float f32x4;    // MFMA C/D frag
typedef __attribute__((ext_vector_type(4))) unsigned int u32x4;

// ---- workspace layout (all 16B aligned) ----
// Apk: [b*12+s][kt<28][af<4][lane<64] x 16B  = 384*28*4*1024 = 44,040,192
// Bpk: [bx2<14][seg<3][kt<28][bfi<4][lane]   = 14*3*28*4*1024 = 4,816,896
// Wpk: [(gi*8+df)*2+kc][lane]                = 48*1024 = 49,152
#define WS_A_OFF   0ull
#define WS_A_BYTES 44040192ull
#define WS_B_OFF   (WS_A_OFF + WS_A_BYTES)
#define WS_B_BYTES 4816896ull
#define WS_W_OFF   (WS_B_OFF + WS_B_BYTES)
#define WS_W_BYTES 49152ull
#define WS_NEED    (WS_W_OFF + WS_W_BYTES)   // 48,906,240

__device__ __forceinline__ unsigned short f2bf(float f) {
    union { float f; unsigned int u; } v; v.f = f;
    unsigned int r = v.u + 0x7fffu + ((v.u >> 16) & 1u);   // RNE
    return (unsigned short)(r >> 16);
}

// async global->LDS, 16B per lane. LDS dest is wave-uniform base + lane*16
// (HW-applied); global src is per-lane. Counted by vmcnt.
__device__ __forceinline__ void gload_lds16(const void* g, void* l) {
    __builtin_amdgcn_global_load_lds(
        (const __attribute__((address_space(1))) void*)g,
        (__attribute__((address_space(3))) void*)l,
        16, 0, 0);
}

// ---------------- prep kernels ----------------

// A-pack: h = x + temb + semb per (b, s, c-half), bf16, MFMA A-fragment order.
__global__ __launch_bounds__(256) void prep_a(const float* __restrict__ x,
                                              const float* __restrict__ temb,
                                              const float* __restrict__ semb,
                                              bf16x8* __restrict__ Apk) {
    __shared__ short hs[32 * 904];          // 57,856 B (row pad 904: bank spread)
    const int tid = threadIdx.x;
    const int bs  = blockIdx.x >> 1;        // 0..383 = b*12 + s
    const int ch  = blockIdx.x & 1;         // channel half
    const int b   = bs / 12, s = bs - b * 12;

    for (int cl = 0; cl < 32; ++cl) {
        const int c = ch * 32 + cl;
        const float te = temb[c * T_ + s];
        const float* xr = x + ((size_t)(b * C_ + c) * T_ + s) * NV;
        const float* sr = semb + (size_t)c * NV;
        for (int k = tid; k < 896; k += 256) {
            float v = (k < NV) ? (xr[k] + te + sr[k]) : 0.f;
            hs[cl * 904 + k] = (short)f2bf(v);
        }
    }
    __syncthreads();
    // frags for this half: kt<28 x a2<2 x lane<64 = 3584
    for (int i = tid; i < 3584; i += 256) {
        const int lane = i & 63;
        const int chunk = i >> 6;           // kt*2 + a2
        const int kt = chunk >> 1, a2 = chunk & 1;
        const int af = ch * 2 + a2;
        const int cl = a2 * 16 + (lane & 15);
        const int k0 = kt * 32 + (lane >> 4) * 8;
        const bf16x8 vv = *(const bf16x8*)&hs[cl * 904 + k0];
        Apk[(size_t)((bs * KSEG + kt) * 4 + af) * 64 + lane] = vv;
    }
}

// B-pack + W-pack fused (one fewer dispatch).
// blocks 0..1175: adj middle rows -> bf16 B-fragments per time-segment.
// blocks 1176..1187: W -> bf16 B-fragments.
__global__ __launch_bounds__(256) void prep_bw(const float* __restrict__ adj,
                                               const float* __restrict__ W,
                                               u32x4* __restrict__ Bpk,
                                               u32x4* __restrict__ Wpk) {
    const int l = threadIdx.x & 63;
    if (blockIdx.x < 1176) {
        const int chunk = blockIdx.x * 4 + (threadIdx.x >> 6);   // 0..4703
        const int bfi = chunk & 3;
        int tmp = chunk >> 2;
        const int kt = tmp % KSEG;  tmp /= KSEG;
        const int seg = tmp % 3;
        const int bx2 = tmp / 3;                                  // 0..13
        const int m16 = bx2 * 4 + bfi;                            // 0..55
        const int row = NV + m16 * 16 + (l & 15);                 // <= 1778 < 2649
        const float* src = adj + (size_t)row * K3 + seg * NV;
        const int k0 = kt * 32 + (l >> 4) * 8;
        unsigned short u[8];
#pragma unroll
        for (int i = 0; i < 8; ++i) {
            const int kk = k0 + i;
            u[i] = (kk < NV) ? f2bf(src[kk]) : (unsigned short)0;
        }
        u32x4 pk;
        pk[0] = u[0] | ((unsigned)u[1] << 16);
        pk[1] = u[2] | ((unsigned)u[3] << 16);
        pk[2] = u[4] | ((unsigned)u[5] << 16);
        pk[3] = u[6] | ((unsigned)u[7] << 16);
        Bpk[(size_t)chunk * 64 + l] = pk;
    } else {
        const int chunk = (blockIdx.x - 1176) * 4 + (threadIdx.x >> 6);   // 0..47
        const int c24 = chunk >> 1;
        const int kc  = chunk & 1;
        const int gi  = c24 >> 3;
        const int df  = c24 & 7;
        const int d   = 16 * df + (l & 15);
        const int c0  = kc * 32 + (l >> 4) * 8;
        const float* src = W + (size_t)gi * C_ * 128 + d;
        unsigned short u[8];
#pragma unroll
        for (int i = 0; i < 8; ++i) u[i] = f2bf(src[(size_t)(c0 + i) * 128]);
        u32x4 pk;
        pk[0] = u[0] | ((unsigned)u[1] << 16);
        pk[1] = u[2] | ((unsigned)u[3] << 16);
        pk[2] = u[4] | ((unsigned)u[5] << 16);
        pk[3] = u[6] | ((unsigned)u[7] << 16);
        Wpk[(size_t)chunk * 64 + l] = pk;
    }
}

// ---------------- main kernel: split-path staged GEMM + fused GLU epilogue ----------------
// block = 256 threads = 4 waves = 2 bt x 2 m-halves (128 m); wave = 64 m x 1 bt.
// ROUND-6 STRUCTURE: stage 1 is LDS-READ-BW bound (round 4/5 PMC model:
// per-CU phase rhythm == LDS bytes / 85 B/cyc). Fix: only A goes through
// LDS (8 KB staged, 16 KB read per block-phase); B-frags load straight to
// REGISTERS from global (16 KB/block-phase on the otherwise-idle L1 pipe,
// double-buffered one step ahead). LDS traffic halves: 48 -> 24 KB/block-phase.
// vmcnt discipline per phase: [issue 4 B-reg loads (st+1)] [wait vmcnt(4);
// s_barrier] [issue 2 A-lds (st+1)] [ds_read A(st)] [16 MFMA @ setprio(1)].
// The wait drains exactly {A[st](2), B[st](4)}, leaves B[st+1](4) in flight.
// LDS = union(A dbuf 16 KB, gs 36,864) = 36,864 B -> 4 blocks/CU; VGPR capped
// 128 via __launch_bounds__(256,4) -> 16 waves/CU target.
__global__ __launch_bounds__(256, 4) void stsgcl_main(
    const bf16x8* __restrict__ Apk,
    const bf16x8* __restrict__ Bpk,
    const bf16x8* __restrict__ Wpk,
    const float* __restrict__ bias,
    float* __restrict__ out)
{
    __shared__ union {
        short stage[2][8][512];    // A dbuf: 2 bufs x 8 frags x 1 KB = 16,384 B
        short gs[4][64 * 72];      // per-wave 64m x 72c bf16 = 36,864 B
    } sm;

    const int tid  = threadIdx.x;
    const int lane = tid & 63;
    const int w    = tid >> 6;              // 0..3
    const int q    = lane >> 4;
    const int lo   = lane & 15;
    const int btl  = w >> 1;                // bt within pair
    const int mh   = w & 1;                 // 64-m half

    // XCD-aware decode (1120 = 8 XCDs * 20 pair-groups * 7 m-blocks)
    const int flat = blockIdx.x;
    const int xcd  = flat & 7;
    const int idx  = flat >> 3;             // 0..139
    const int grp  = idx / 7;               // 0..19
    const int bx   = idx - grp * 7;         // 0..6
    const int pair = xcd * 20 + grp;        // 0..159
    const int bt   = pair * 2 + btl;        // 0..319
    const int bb   = bt / TTW;
    const int t    = bt - bb * TTW;
    const int bx2  = bx * 2 + mh;           // 0..13

    f32x4 acc[4][4];
#pragma unroll
    for (int i = 0; i < 4; ++i)
#pragma unroll
        for (int j = 0; j < 4; ++j)
#pragma unroll
            for (int r = 0; r < 4; ++r) acc[i][j][r] = 0.f;

    // ---- stage 1: 84 k-steps (3 segs x 28 kt contiguous) ----
    // A staging: 8 frags/step (2 bt x 4 af); wave w stages frags 2w, 2w+1.
    const int f0 = 2 * w, f1 = f0 + 1;
    const char *sA0, *sA1;
    {
        const int btq0 = pair * 2 + (f0 >> 2);
        const int bb0 = btq0 / TTW, t0 = btq0 - bb0 * TTW;
        sA0 = (const char*)(Apk + (size_t)((bb0 * T_ + t0) * KSEG) * 256)
              + (f0 & 3) * 1024 + (size_t)lane * 16;
        const int btq1 = pair * 2 + (f1 >> 2);
        const int bb1 = btq1 / TTW, t1 = btq1 - bb1 * TTW;
        sA1 = (const char*)(Apk + (size_t)((bb1 * T_ + t1) * KSEG) * 256)
              + (f1 & 3) * 1024 + (size_t)lane * 16;
    }
    // B: this wave's own 4 m-frags of panel bx2, direct global->reg (1 KB each)
    const bf16x8* bp = Bpk + (size_t)(bx2 * 3 * KSEG) * 256 + lane;

    bf16x8 bA[4], bB[4], av[4];

    // prologue: B[0] -> bA (4 reg loads), A[0] -> buf0 (2 lds loads)
#pragma unroll
    for (int j = 0; j < 4; ++j) bA[j] = bp[j * 64];
    bp += 256;
    gload_lds16(sA0, &sm.stage[0][f0][0]);
    gload_lds16(sA1, &sm.stage[0][f1][0]);
    sA0 += 4096; sA1 += 4096;

    const int ga = btl * 4;                 // A frag group for this wave

#define MFMA16(BSET)                                                             \
    do {                                                                         \
        __builtin_amdgcn_s_setprio(1);                                           \
        _Pragma("unroll")                                                        \
        for (int i = 0; i < 4; ++i)                                              \
            _Pragma("unroll")                                                    \
            for (int j = 0; j < 4; ++j)                                          \
                acc[i][j] = __builtin_amdgcn_mfma_f32_16x16x32_bf16(             \
                    av[i], BSET[j], acc[i][j], 0, 0, 0);                         \
        __builtin_amdgcn_s_setprio(0);                                           \
    } while (0)

#pragma unroll 1
    for (int st = 0; st < 82; st += 2) {
        // even phase: compute step st (buf0, bA); prefetch st+1
#pragma unroll
        for (int j = 0; j < 4; ++j) bB[j] = bp[j * 64];
        bp += 256;
        asm volatile("s_waitcnt vmcnt(4)\n\ts_barrier" ::: "memory");
        gload_lds16(sA0, &sm.stage[1][f0][0]);
        gload_lds16(sA1, &sm.stage[1][f1][0]);
        sA0 += 4096; sA1 += 4096;
#pragma unroll
        for (int i = 0; i < 4; ++i) av[i] = *(const bf16x8*)&sm.stage[0][ga + i][lane << 3];
        MFMA16(bA);

        // odd phase: compute step st+1 (buf1, bB); prefetch st+2
#pragma unroll
        for (int j = 0; j < 4; ++j) bA[j] = bp[j * 64];
        bp += 256;
        asm volatile("s_waitcnt vmcnt(4)\n\ts_barrier" ::: "memory");
        gload_lds16(sA0, &sm.stage[0][f0][0]);
        gload_lds16(sA1, &sm.stage[0][f1][0]);
        sA0 += 4096; sA1 += 4096;
#pragma unroll
        for (int i = 0; i < 4; ++i) av[i] = *(const bf16x8*)&sm.stage[1][ga + i][lane << 3];
        MFMA16(bB);
    }
    // peeled phase 82 (even): compute buf0/bA; prefetch step 83 only
    {
#pragma unroll
        for (int j = 0; j < 4; ++j) bB[j] = bp[j * 64];
        asm volatile("s_waitcnt vmcnt(4)\n\ts_barrier" ::: "memory");
        gload_lds16(sA0, &sm.stage[1][f0][0]);
        gload_lds16(sA1, &sm.stage[1][f1][0]);
#pragma unroll
        for (int i = 0; i < 4; ++i) av[i] = *(const bf16x8*)&sm.stage[0][ga + i][lane << 3];
        MFMA16(bA);
    }
    // peeled phase 83 (odd): full drain, compute buf1/bB
    {
        asm volatile("s_waitcnt vmcnt(0)\n\ts_barrier" ::: "memory");
#pragma unroll
        for (int i = 0; i < 4; ++i) av[i] = *(const bf16x8*)&sm.stage[1][ga + i][lane << 3];
        MFMA16(bB);
    }
#undef MFMA16
    __syncthreads();   // all waves done with stage bufs before gs overwrite

    // ---- transpose g (D-layout: c rows x m cols) -> gs[w][m][c] bf16 ----
    short* gw = &sm.gs[w][0];
#pragma unroll
    for (int af = 0; af < 4; ++af)
#pragma unroll
        for (int bf = 0; bf < 4; ++bf) {
            uint2 pk;
            pk.x = (unsigned)f2bf(acc[af][bf][0]) | ((unsigned)f2bf(acc[af][bf][1]) << 16);
            pk.y = (unsigned)f2bf(acc[af][bf][2]) | ((unsigned)f2bf(acc[af][bf][3]) << 16);
            *(uint2*)&gw[(16 * bf + lo) * 72 + 16 * af + 4 * q] = pk;   // c = 16af+4q+r, m = 16bf+lo
        }
    // same-wave RAW through LDS: compiler orders via lgkmcnt

    // ---- stage 2 per m-group: z = g^T . W[gi], GLU, max over branches, store ----
#pragma unroll 1
    for (int mg = 0; mg < 4; ++mg) {
        const short* arow = &gw[(16 * mg + lo) * 72];
        const bf16x8 a2k0 = *(const bf16x8*)&arow[q * 8];        // c = 0..31
        const bf16x8 a2k1 = *(const bf16x8*)&arow[32 + q * 8];   // c = 32..63

        float om[4][4];
#pragma unroll
        for (int i = 0; i < 4; ++i)
#pragma unroll
            for (int r = 0; r < 4; ++r) om[i][r] = -3.4e38f;

#pragma unroll 1
        for (int gi = 0; gi < 3; ++gi) {
            f32x4 z[8];
#pragma unroll
            for (int i = 0; i < 8; ++i)
#pragma unroll
                for (int r = 0; r < 4; ++r) z[i][r] = 0.f;
#pragma unroll
            for (int df = 0; df < 8; ++df) {
                z[df] = __builtin_amdgcn_mfma_f32_16x16x32_bf16(
                    a2k0, Wpk[(size_t)(((gi * 8 + df) * 2 + 0)) * 64 + lane], z[df], 0, 0, 0);
                z[df] = __builtin_amdgcn_mfma_f32_16x16x32_bf16(
                    a2k1, Wpk[(size_t)(((gi * 8 + df) * 2 + 1)) * 64 + lane], z[df], 0, 0, 0);
            }
#pragma unroll
            for (int df = 0; df < 4; ++df) {
                const float b1 = bias[gi * 128 + 16 * df + lo];
                const float b2 = bias[gi * 128 + 64 + 16 * df + lo];
#pragma unroll
                for (int r = 0; r < 4; ++r) {
                    const float z1 = z[df][r] + b1;
                    const float z2 = z[df + 4][r] + b2;
                    const float sg = 1.0f / (1.0f + __expf(-z2));
                    om[df][r] = fmaxf(om[df][r], z1 * sg);
                }
            }
        }

        const int m16g = bx * 8 + mh * 4 + mg;      // 0..55
        const int mvb  = m16g * 16 + 4 * q;         // D row = 4q + r
#pragma unroll
        for (int df = 0; df < 4; ++df) {
            const int cout = 16 * df + lo;
            float* orow = out + ((size_t)(bb * C_ + cout) * TTW + t) * NV + mvb;
#pragma unroll
            for (int r = 0; r < 4; ++r) {
                if (mvb + r < NV) orow[r] = om[df][r];
            }
        }
    }
}

// ---------------- fallback: round-1 verified fp32 kernel (tiny ws) ----------------
__global__ __launch_bounds__(256) void stsgcl_fused(
    const float* __restrict__ x, const float* __restrict__ temb,
    const float* __restrict__ semb, const float* __restrict__ adj,
    const float* __restrict__ Wg, const float* __restrict__ bias,
    float* __restrict__ out)
{
    __shared__ union {
        struct { float As[32][64]; float Bs[32][64]; } s1;
        float Ws[64][128];
    } sm;
    __shared__ float Gsf[64][64];

    const int tid = threadIdx.x;
    const int bt = blockIdx.y;
    const int bb = bt / TTW;
    const int t  = bt % TTW;
    const int m0 = blockIdx.x * 64;
    const int tr = tid >> 4, tc = tid & 15;
    const int lrow = tid >> 2;
    const int kq = (tid & 3) * 8;

    const float* xrow = x + ((size_t)(bb * C_ + lrow) * T_ + t) * NV;
    const float* brow = adj + (size_t)(NV + m0 + lrow) * K3;
    const float* srow = semb + (size_t)lrow * NV;
    const float te0 = temb[lrow * T_ + t], te1 = temb[lrow * T_ + t + 1], te2 = temb[lrow * T_ + t + 2];

    float acc[4][4];
#pragma unroll
    for (int i = 0; i < 4; ++i)
#pragma unroll
        for (int j = 0; j < 4; ++j) acc[i][j] = 0.f;

    for (int kt = 0; kt < (K3 + 31) / 32; ++kt) {
        const int kg0 = kt * 32 + kq;
        {
            int tt, n;
            if (kg0 >= 2 * NV) { tt = 2; n = kg0 - 2 * NV; }
            else if (kg0 >= NV) { tt = 1; n = kg0 - NV; }
            else { tt = 0; n = kg0; }
#pragma unroll
            for (int i = 0; i < 8; ++i) {
                float v = 0.f;
                if (kg0 + i < K3) {
                    const float tev = (tt == 0) ? te0 : ((tt == 1) ? te1 : te2);
                    v = xrow[tt * NV + n] + tev + srow[n];
                }
                sm.s1.As[kq + i][lrow] = v;
                if (++n == NV) { n = 0; ++tt; }
            }
        }
#pragma unroll
        for (int i = 0; i < 8; ++i) sm.s1.Bs[kq + i][lrow] = brow[kg0 + i];
        __syncthreads();
#pragma unroll
        for (int kk = 0; kk < 32; ++kk) {
            const float4 a = *(const float4*)&sm.s1.As[kk][tr * 4];
            const float4 bv = *(const float4*)&sm.s1.Bs[kk][tc * 4];
            const float av[4] = {a.x, a.y, a.z, a.w};
            const float bw[4] = {bv.x, bv.y, bv.z, bv.w};
#pragma unroll
            for (int i = 0; i < 4; ++i)
#pragma unroll
                for (int j = 0; j < 4; ++j) acc[i][j] += av[i] * bw[j];
        }
        __syncthreads();
    }
#pragma unroll
    for (int i = 0; i < 4; ++i)
#pragma unroll
        for (int j = 0; j < 4; ++j) Gsf[tr * 4 + i][tc * 4 + j] = acc[i][j];

    const int pg = tid & 15, cg = tid >> 4;
    float omax[4][4];
#pragma unroll
    for (int i = 0; i < 4; ++i)
#pragma unroll
        for (int j = 0; j < 4; ++j) omax[i][j] = -3.4e38f;

    for (int gi = 0; gi < 3; ++gi) {
        __syncthreads();
        {
            const float4* wsrc = (const float4*)(Wg + (size_t)gi * C_ * 128);
            float4* wdst = (float4*)&sm.Ws[0][0];
#pragma unroll
            for (int i = 0; i < 8; ++i) wdst[tid + i * 256] = wsrc[tid + i * 256];
        }
        __syncthreads();
        float z1[4][4], z2[4][4];
#pragma unroll
        for (int j = 0; j < 4; ++j) {
            const float b1 = bias[gi * 128 + cg * 4 + j];
            const float b2 = bias[gi * 128 + 64 + cg * 4 + j];
#pragma unroll
            for (int i = 0; i < 4; ++i) { z1[i][j] = b1; z2[i][j] = b2; }
        }
#pragma unroll 8
        for (int cc = 0; cc < 64; ++cc) {
            const float4 gv = *(const float4*)&Gsf[cc][pg * 4];
            const float4 w1 = *(const float4*)&sm.Ws[cc][cg * 4];
            const float4 w2 = *(const float4*)&sm.Ws[cc][64 + cg * 4];
            const float gva[4] = {gv.x, gv.y, gv.z, gv.w};
            const float w1a[4] = {w1.x, w1.y, w1.z, w1.w};
            const float w2a[4] = {w2.x, w2.y, w2.z, w2.w};
#pragma unroll
            for (int i = 0; i < 4; ++i)
#pragma unroll
                for (int j = 0; j < 4; ++j) { z1[i][j] += gva[i] * w1a[j]; z2[i][j] += gva[i] * w2a[j]; }
        }
#pragma unroll
        for (int i = 0; i < 4; ++i)
#pragma unroll
            for (int j = 0; j < 4; ++j) {
                const float s = 1.0f / (1.0f + __expf(-z2[i][j]));
                omax[i][j] = fmaxf(omax[i][j], z1[i][j] * s);
            }
    }
    const int mmb = m0 + pg * 4;
#pragma unroll
    for (int j = 0; j < 4; ++j) {
        const int co = cg * 4 + j;
        float* orow = out + ((size_t)(bb * C_ + co) * TTW + t) * NV;
#pragma unroll
        for (int i = 0; i < 4; ++i) {
            const int mm = mmb + i;
            if (mm < NV) orow[mm] = omax[i][j];
        }
    }
}

extern "C" void kernel_launch(void* const* d_in, const int* in_sizes, int n_in,
                              void* d_out, int out_size, void* d_ws, size_t ws_size,
                              hipStream_t stream) {
    (void)in_sizes; (void)n_in; (void)out_size;
    const float* x    = (const float*)d_in[0];
    const float* temb = (const float*)d_in[1];
    const float* semb = (const float*)d_in[2];
    const float* adj  = (const float*)d_in[3];
    const float* Wg   = (const float*)d_in[4];
    const float* bias = (const float*)d_in[5];
    float* out = (float*)d_out;

    if (ws_size >= (size_t)WS_NEED) {
        bf16x8* Apk = (bf16x8*)((char*)d_ws + WS_A_OFF);
        u32x4*  Bpk = (u32x4*)((char*)d_ws + WS_B_OFF);
        u32x4*  Wpk = (u32x4*)((char*)d_ws + WS_W_OFF);

        prep_a<<<dim3(768), 256, 0, stream>>>(x, temb, semb, Apk);
        prep_bw<<<dim3(1188), 256, 0, stream>>>(adj, Wg, Bpk, Wpk);

        stsgcl_main<<<dim3(1120), 256, 0, stream>>>(Apk, (const bf16x8*)Bpk, (const bf16x8*)Wpk, bias, out);
    } else {
        dim3 grid(14, B_ * TTW);
        stsgcl_fused<<<grid, 256, 0, stream>>>(x, temb, semb, adj, Wg, bias, out);
    }
}

// Round 7
// 380.921 us; speedup vs baseline: 1.2379x; 1.2379x over previous
//
#include <hip/hip_runtime.h>
#include <math.h>

#define B_   32
#define C_   64
#define T_   12
#define NV   883
#define TTW  10          // T-2 output time steps
#define K3   2649        // 3*NV
#define KSEG 28          // k-tiles per 883-segment (28*32=896, zero-padded)

typedef __attribute__((ext_vector_type(8))) short bf16x8;   // 8 bf16 = 4 VGPRs (MFMA A/B frag)
typedef __attribute__((ext_vector_type(4))) float f32x4;    // MFMA C/D frag
typedef __attribute__((ext_vector_type(4))) unsigned int u32x4;

// ---- workspace layout (all 16B aligned) ----
// Apk: [b*12+s][kt<28][af<4][lane<64] x 16B  = 384*28*4*1024 = 44,040,192
// Bpk: [bx2<14][seg<3][kt<28][bfi<4][lane]   = 14*3*28*4*1024 = 4,816,896
// Wpk: [(gi*8+df)*2+kc][lane]                = 48*1024 = 49,152
#define WS_A_OFF   0ull
#define WS_A_BYTES 44040192ull
#define WS_B_OFF   (WS_A_OFF + WS_A_BYTES)
#define WS_B_BYTES 4816896ull
#define WS_W_OFF   (WS_B_OFF + WS_B_BYTES)
#define WS_W_BYTES 49152ull
#define WS_NEED    (WS_W_OFF + WS_W_BYTES)   // 48,906,240

__device__ __forceinline__ unsigned short f2bf(float f) {
    union { float f; unsigned int u; } v; v.f = f;
    unsigned int r = v.u + 0x7fffu + ((v.u >> 16) & 1u);   // RNE
    return (unsigned short)(r >> 16);
}

// async global->LDS, 16B per lane. LDS dest is wave-uniform base + lane*16
// (HW-applied); global src is per-lane. Counted by vmcnt.
__device__ __forceinline__ void gload_lds16(const void* g, void* l) {
    __builtin_amdgcn_global_load_lds(
        (const __attribute__((address_space(1))) void*)g,
        (__attribute__((address_space(3))) void*)l,
        16, 0, 0);
}

// ---------------- prep kernels ----------------

// A-pack v2: h = x + temb + semb, bf16, MFMA A-fragment order.
// grid = 384*4 blocks (one per (bs, af)); 16 rows x 896 cols per block.
// Per-thread: 56 INDEPENDENT scalar loads unrolled x14 (deep MLP — the v1
// serial cl-loop was latency-serialized on HBM-cold x). 29 KB LDS -> 5/CU.
__global__ __launch_bounds__(256) void prep_a(const float* __restrict__ x,
                                              const float* __restrict__ temb,
                                              const float* __restrict__ semb,
                                              bf16x8* __restrict__ Apk) {
    __shared__ short hs[16 * 904];          // 28,928 B (row pad 904: bank spread)
    const int tid = threadIdx.x;
    const int bs  = blockIdx.x >> 2;        // 0..383 = b*12 + s
    const int ch2 = blockIdx.x & 3;
    const int ch  = ch2 >> 1, a2 = ch2 & 1;
    const int af  = ch * 2 + a2;            // 0..3
    const int b   = bs / 12, s = bs - b * 12;

    const int cl = tid >> 4;                // 0..15 (row)
    const int kq = tid & 15;                // 0..15
    const int c  = ch * 32 + a2 * 16 + cl;
    const float te = temb[c * T_ + s];
    const float* xr = x + ((size_t)(b * C_ + c) * T_ + s) * NV;
    const float* sr = semb + (size_t)c * NV;
    short* hrow = &hs[cl * 904];
#pragma unroll 14
    for (int i = 0; i < 56; ++i) {
        const int k = kq + 16 * i;          // 0..895
        float v = 0.f;
        if (k < NV) v = xr[k] + te + sr[k];
        hrow[k] = (short)f2bf(v);
    }
    __syncthreads();
    // frags for this af: kt<28 x lane<64 = 1792; 7 per thread
    for (int i = tid; i < 1792; i += 256) {
        const int lane = i & 63;
        const int kt = i >> 6;
        const int k0 = kt * 32 + (lane >> 4) * 8;
        const bf16x8 vv = *(const bf16x8*)&hs[(lane & 15) * 904 + k0];
        Apk[(size_t)((bs * KSEG + kt) * 4 + af) * 64 + lane] = vv;
    }
}

// B-pack + W-pack fused.
// blocks 0..1175: adj middle rows -> bf16 B-fragments per time-segment.
// blocks 1176..1187: W -> bf16 B-fragments.
__global__ __launch_bounds__(256) void prep_bw(const float* __restrict__ adj,
                                               const float* __restrict__ W,
                                               u32x4* __restrict__ Bpk,
                                               u32x4* __restrict__ Wpk) {
    const int l = threadIdx.x & 63;
    if (blockIdx.x < 1176) {
        const int chunk = blockIdx.x * 4 + (threadIdx.x >> 6);   // 0..4703
        const int bfi = chunk & 3;
        int tmp = chunk >> 2;
        const int kt = tmp % KSEG;  tmp /= KSEG;
        const int seg = tmp % 3;
        const int bx2 = tmp / 3;                                  // 0..13
        const int m16 = bx2 * 4 + bfi;                            // 0..55
        const int row = NV + m16 * 16 + (l & 15);                 // <= 1778 < 2649
        const float* src = adj + (size_t)row * K3 + seg * NV;
        const int k0 = kt * 32 + (l >> 4) * 8;
        unsigned short u[8];
#pragma unroll
        for (int i = 0; i < 8; ++i) {
            const int kk = k0 + i;
            u[i] = (kk < NV) ? f2bf(src[kk]) : (unsigned short)0;
        }
        u32x4 pk;
        pk[0] = u[0] | ((unsigned)u[1] << 16);
        pk[1] = u[2] | ((unsigned)u[3] << 16);
        pk[2] = u[4] | ((unsigned)u[5] << 16);
        pk[3] = u[6] | ((unsigned)u[7] << 16);
        Bpk[(size_t)chunk * 64 + l] = pk;
    } else {
        const int chunk = (blockIdx.x - 1176) * 4 + (threadIdx.x >> 6);   // 0..47
        const int c24 = chunk >> 1;
        const int kc  = chunk & 1;
        const int gi  = c24 >> 3;
        const int df  = c24 & 7;
        const int d   = 16 * df + (l & 15);
        const int c0  = kc * 32 + (l >> 4) * 8;
        const float* src = W + (size_t)gi * C_ * 128 + d;
        unsigned short u[8];
#pragma unroll
        for (int i = 0; i < 8; ++i) u[i] = f2bf(src[(size_t)(c0 + i) * 128]);
        u32x4 pk;
        pk[0] = u[0] | ((unsigned)u[1] << 16);
        pk[1] = u[2] | ((unsigned)u[3] << 16);
        pk[2] = u[4] | ((unsigned)u[5] << 16);
        pk[3] = u[6] | ((unsigned)u[7] << 16);
        Wpk[(size_t)chunk * 64 + l] = pk;
    }
}

// ---------------- main kernel: barrier-free self-staged GEMM + fused GLU epilogue ----------------
// block = 256 threads = 4 waves = 2 bt x 2 m-halves; wave = 64 m x 1 bt.
// ROUND-7 STRUCTURE: R4's barrier-per-phase locked all waves into the same
// phase position -> the CU's pipes (matrix 28%, LDS 35%, VMEM 23%, VALU 34%)
// ran SERIALLY (sum == measured 3330-cyc block-phase wall). Fix: NO BARRIER
// in the k-loop. Each wave stages its OWN 8 frags (4 A of its bt + 4 B of its
// mh) into a PRIVATE 16 KB 2-buffer LDS ring and self-syncs with vmcnt(8).
// Waves free-run and drift -> inter-wave pipe overlap. Staging duplicates 2x
// (FETCH ~2x, still far below BW ceiling; panels L2-warm via XCD swizzle).
// WAR (DMA overwriting a buffer with pending ds_reads) is fenced by an
// explicit lgkmcnt(0)+memory-clobber before each issue. All LDS offsets are
// compile-time immediates (unroll-2 parity).
__global__ __launch_bounds__(256, 2) void stsgcl_main(
    const bf16x8* __restrict__ Apk,
    const bf16x8* __restrict__ Bpk,
    const bf16x8* __restrict__ Wpk,
    const float* __restrict__ bias,
    float* __restrict__ out)
{
    __shared__ union {
        short stage[4][2][8][512];   // [wave][buf][frag][1 KB] = 65,536 B
        short gs[4][64 * 72];        // per-wave 64m x 72c bf16 = 36,864 B
    } sm;

    const int tid  = threadIdx.x;
    const int lane = tid & 63;
    const int w    = tid >> 6;              // 0..3
    const int q    = lane >> 4;
    const int lo   = lane & 15;
    const int btl  = w >> 1;                // bt within pair
    const int mh   = w & 1;                 // 64-m half

    // XCD-aware decode (1120 = 8 XCDs * 20 pair-groups * 7 m-blocks)
    const int flat = blockIdx.x;
    const int xcd  = flat & 7;
    const int idx  = flat >> 3;             // 0..139
    const int grp  = idx / 7;               // 0..19
    const int bx   = idx - grp * 7;         // 0..6
    const int pair = xcd * 20 + grp;        // 0..159
    const int bt   = pair * 2 + btl;        // 0..319
    const int bb   = bt / TTW;
    const int t    = bt - bb * TTW;
    const int bx2  = bx * 2 + mh;           // 0..13

    f32x4 acc[4][4];
#pragma unroll
    for (int i = 0; i < 4; ++i)
#pragma unroll
        for (int j = 0; j < 4; ++j)
#pragma unroll
            for (int r = 0; r < 4; ++r) acc[i][j][r] = 0.f;

    // ---- stage 1: 84 k-steps (3 segs x 28 kt contiguous), per-wave ring-2 ----
    const char* pA = (const char*)(Apk + (size_t)((bb * T_ + t) * KSEG) * 256)
                     + (size_t)lane * 16;
    const char* pB = (const char*)(Bpk + (size_t)(bx2 * 3 * KSEG) * 256)
                     + (size_t)lane * 16;
    short* lw = &sm.stage[w][0][0][0];      // wave-private 16 KB
    const short* lr = lw + lane * 8;        // lane read slice

    // issue one step's 8 frags into buf LB (0/1); bumps pA/pB by 4096 B
#define ISSUE(LB) do {                                        \
        gload_lds16(pA,        lw + (LB)*4096 + 0*512);       \
        gload_lds16(pA + 1024, lw + (LB)*4096 + 1*512);       \
        gload_lds16(pA + 2048, lw + (LB)*4096 + 2*512);       \
        gload_lds16(pA + 3072, lw + (LB)*4096 + 3*512);       \
        gload_lds16(pB,        lw + (LB)*4096 + 4*512);       \
        gload_lds16(pB + 1024, lw + (LB)*4096 + 5*512);       \
        gload_lds16(pB + 2048, lw + (LB)*4096 + 6*512);       \
        gload_lds16(pB + 3072, lw + (LB)*4096 + 7*512);       \
        pA += 4096; pB += 4096; } while (0)

#define COMPUTE(LB) do {                                                          \
        bf16x8 av[4], bv[4];                                                      \
        _Pragma("unroll")                                                         \
        for (int i = 0; i < 4; ++i) av[i] = *(const bf16x8*)&lr[(LB)*4096 + i*512];      \
        _Pragma("unroll")                                                         \
        for (int j = 0; j < 4; ++j) bv[j] = *(const bf16x8*)&lr[(LB)*4096 + (4+j)*512];  \
        __builtin_amdgcn_s_setprio(1);                                            \
        _Pragma("unroll")                                                         \
        for (int i = 0; i < 4; ++i)                                               \
            _Pragma("unroll")                                                     \
            for (int j = 0; j < 4; ++j)                                           \
                acc[i][j] = __builtin_amdgcn_mfma_f32_16x16x32_bf16(              \
                    av[i], bv[j], acc[i][j], 0, 0, 0);                            \
        __builtin_amdgcn_s_setprio(0); } while (0)

    // prologue: step 0 -> buf 0
    ISSUE(0);

#pragma unroll 1
    for (int st = 0; st < 82; st += 2) {
        // phase A: prefetch st+1 -> buf1; compute st from buf0.
        // lgkm fence: buf1's previous readers (st-1) complete before overwrite.
        asm volatile("s_waitcnt lgkmcnt(0)" ::: "memory");
        ISSUE(1);
        asm volatile("s_waitcnt vmcnt(8)" ::: "memory");   // step st staged
        COMPUTE(0);
        // phase B: prefetch st+2 -> buf0; compute st+1 from buf1
        asm volatile("s_waitcnt lgkmcnt(0)" ::: "memory");
        ISSUE(0);
        asm volatile("s_waitcnt vmcnt(8)" ::: "memory");   // step st+1 staged
        COMPUTE(1);
    }
    // peeled step 82 (buf0): prefetch 83 -> buf1
    {
        asm volatile("s_waitcnt lgkmcnt(0)" ::: "memory");
        ISSUE(1);
        asm volatile("s_waitcnt vmcnt(8)" ::: "memory");
        COMPUTE(0);
    }
    // peeled step 83 (buf1): full drain
    {
        asm volatile("s_waitcnt vmcnt(0)" ::: "memory");
        COMPUTE(1);
    }
#undef ISSUE
#undef COMPUTE
    __syncthreads();   // all waves done with stage bufs before gs overwrite

    // ---- transpose g (D-layout: c rows x m cols) -> gs[w][m][c] bf16 ----
    short* gw = &sm.gs[w][0];
#pragma unroll
    for (int af = 0; af < 4; ++af)
#pragma unroll
        for (int bf = 0; bf < 4; ++bf) {
            uint2 pk;
            pk.x = (unsigned)f2bf(acc[af][bf][0]) | ((unsigned)f2bf(acc[af][bf][1]) << 16);
            pk.y = (unsigned)f2bf(acc[af][bf][2]) | ((unsigned)f2bf(acc[af][bf][3]) << 16);
            *(uint2*)&gw[(16 * bf + lo) * 72 + 16 * af + 4 * q] = pk;   // c = 16af+4q+r, m = 16bf+lo
        }
    // same-wave RAW through LDS: compiler orders via lgkmcnt

    // ---- stage 2 per m-group: z = g^T . W[gi], GLU, max over branches, store ----
#pragma unroll 1
    for (int mg = 0; mg < 4; ++mg) {
        const short* arow = &gw[(16 * mg + lo) * 72];
        const bf16x8 a2k0 = *(const bf16x8*)&arow[q * 8];        // c = 0..31
        const bf16x8 a2k1 = *(const bf16x8*)&arow[32 + q * 8];   // c = 32..63

        float om[4][4];
#pragma unroll
        for (int i = 0; i < 4; ++i)
#pragma unroll
            for (int r = 0; r < 4; ++r) om[i][r] = -3.4e38f;

#pragma unroll 1
        for (int gi = 0; gi < 3; ++gi) {
            f32x4 z[8];
#pragma unroll
            for (int i = 0; i < 8; ++i)
#pragma unroll
                for (int r = 0; r < 4; ++r) z[i][r] = 0.f;
#pragma unroll
            for (int df = 0; df < 8; ++df) {
                z[df] = __builtin_amdgcn_mfma_f32_16x16x32_bf16(
                    a2k0, Wpk[(size_t)(((gi * 8 + df) * 2 + 0)) * 64 + lane], z[df], 0, 0, 0);
                z[df] = __builtin_amdgcn_mfma_f32_16x16x32_bf16(
                    a2k1, Wpk[(size_t)(((gi * 8 + df) * 2 + 1)) * 64 + lane], z[df], 0, 0, 0);
            }
#pragma unroll
            for (int df = 0; df < 4; ++df) {
                const float b1 = bias[gi * 128 + 16 * df + lo];
                const float b2 = bias[gi * 128 + 64 + 16 * df + lo];
#pragma unroll
                for (int r = 0; r < 4; ++r) {
                    const float z1 = z[df][r] + b1;
                    const float z2 = z[df + 4][r] + b2;
                    const float sg = 1.0f / (1.0f + __expf(-z2));
                    om[df][r] = fmaxf(om[df][r], z1 * sg);
                }
            }
        }

        const int m16g = bx * 8 + mh * 4 + mg;      // 0..55
        const int mvb  = m16g * 16 + 4 * q;         // D row = 4q + r
#pragma unroll
        for (int df = 0; df < 4; ++df) {
            const int cout = 16 * df + lo;
            float* orow = out + ((size_t)(bb * C_ + cout) * TTW + t) * NV + mvb;
#pragma unroll
            for (int r = 0; r < 4; ++r) {
                if (mvb + r < NV) orow[r] = om[df][r];
            }
        }
    }
}

// ---------------- fallback: round-1 verified fp32 kernel (tiny ws) ----------------
__global__ __launch_bounds__(256) void stsgcl_fused(
    const float* __restrict__ x, const float* __restrict__ temb,
    const float* __restrict__ semb, const float* __restrict__ adj,
    const float* __restrict__ Wg, const float* __restrict__ bias,
    float* __restrict__ out)
{
    __shared__ union {
        struct { float As[32][64]; float Bs[32][64]; } s1;
        float Ws[64][128];
    } sm;
    __shared__ float Gsf[64][64];

    const int tid = threadIdx.x;
    const int bt = blockIdx.y;
    const int bb = bt / TTW;
    const int t  = bt % TTW;
    const int m0 = blockIdx.x * 64;
    const int tr = tid >> 4, tc = tid & 15;
    const int lrow = tid >> 2;
    const int kq = (tid & 3) * 8;

    const float* xrow = x + ((size_t)(bb * C_ + lrow) * T_ + t) * NV;
    const float* brow = adj + (size_t)(NV + m0 + lrow) * K3;
    const float* srow = semb + (size_t)lrow * NV;
    const float te0 = temb[lrow * T_ + t], te1 = temb[lrow * T_ + t + 1], te2 = temb[lrow * T_ + t + 2];

    float acc[4][4];
#pragma unroll
    for (int i = 0; i < 4; ++i)
#pragma unroll
        for (int j = 0; j < 4; ++j) acc[i][j] = 0.f;

    for (int kt = 0; kt < (K3 + 31) / 32; ++kt) {
        const int kg0 = kt * 32 + kq;
        {
            int tt, n;
            if (kg0 >= 2 * NV) { tt = 2; n = kg0 - 2 * NV; }
            else if (kg0 >= NV) { tt = 1; n = kg0 - NV; }
            else { tt = 0; n = kg0; }
#pragma unroll
            for (int i = 0; i < 8; ++i) {
                float v = 0.f;
                if (kg0 + i < K3) {
                    const float tev = (tt == 0) ? te0 : ((tt == 1) ? te1 : te2);
                    v = xrow[tt * NV + n] + tev + srow[n];
                }
                sm.s1.As[kq + i][lrow] = v;
                if (++n == NV) { n = 0; ++tt; }
            }
        }
#pragma unroll
        for (int i = 0; i < 8; ++i) sm.s1.Bs[kq + i][lrow] = brow[kg0 + i];
        __syncthreads();
#pragma unroll
        for (int kk = 0; kk < 32; ++kk) {
            const float4 a = *(const float4*)&sm.s1.As[kk][tr * 4];
            const float4 bv = *(const float4*)&sm.s1.Bs[kk][tc * 4];
            const float av[4] = {a.x, a.y, a.z, a.w};
            const float bw[4] = {bv.x, bv.y, bv.z, bv.w};
#pragma unroll
            for (int i = 0; i < 4; ++i)
#pragma unroll
                for (int j = 0; j < 4; ++j) acc[i][j] += av[i] * bw[j];
        }
        __syncthreads();
    }
#pragma unroll
    for (int i = 0; i < 4; ++i)
#pragma unroll
        for (int j = 0; j < 4; ++j) Gsf[tr * 4 + i][tc * 4 + j] = acc[i][j];

    const int pg = tid & 15, cg = tid >> 4;
    float omax[4][4];
#pragma unroll
    for (int i = 0; i < 4; ++i)
#pragma unroll
        for (int j = 0; j < 4; ++j) omax[i][j] = -3.4e38f;

    for (int gi = 0; gi < 3; ++gi) {
        __syncthreads();
        {
            const float4* wsrc = (const float4*)(Wg + (size_t)gi * C_ * 128);
            float4* wdst = (float4*)&sm.Ws[0][0];
#pragma unroll
            for (int i = 0; i < 8; ++i) wdst[tid + i * 256] = wsrc[tid + i * 256];
        }
        __syncthreads();
        float z1[4][4], z2[4][4];
#pragma unroll
        for (int j = 0; j < 4; ++j) {
            const float b1 = bias[gi * 128 + cg * 4 + j];
            const float b2 = bias[gi * 128 + 64 + cg * 4 + j];
#pragma unroll
            for (int i = 0; i < 4; ++i) { z1[i][j] = b1; z2[i][j] = b2; }
        }
#pragma unroll 8
        for (int cc = 0; cc < 64; ++cc) {
            const float4 gv = *(const float4*)&Gsf[cc][pg * 4];
            const float4 w1 = *(const float4*)&sm.Ws[cc][cg * 4];
            const float4 w2 = *(const float4*)&sm.Ws[cc][64 + cg * 4];
            const float gva[4] = {gv.x, gv.y, gv.z, gv.w};
            const float w1a[4] = {w1.x, w1.y, w1.z, w1.w};
            const float w2a[4] = {w2.x, w2.y, w2.z, w2.w};
#pragma unroll
            for (int i = 0; i < 4; ++i)
#pragma unroll
                for (int j = 0; j < 4; ++j) { z1[i][j] += gva[i] * w1a[j]; z2[i][j] += gva[i] * w2a[j]; }
        }
#pragma unroll
        for (int i = 0; i < 4; ++i)
#pragma unroll
            for (int j = 0; j < 4; ++j) {
                const float s = 1.0f / (1.0f + __expf(-z2[i][j]));
                omax[i][j] = fmaxf(omax[i][j], z1[i][j] * s);
            }
    }
    const int mmb = m0 + pg * 4;
#pragma unroll
    for (int j = 0; j < 4; ++j) {
        const int co = cg * 4 + j;
        float* orow = out + ((size_t)(bb * C_ + co) * TTW + t) * NV;
#pragma unroll
        for (int i = 0; i < 4; ++i) {
            const int mm = mmb + i;
            if (mm < NV) orow[mm] = omax[i][j];
        }
    }
}

extern "C" void kernel_launch(void* const* d_in, const int* in_sizes, int n_in,
                              void* d_out, int out_size, void* d_ws, size_t ws_size,
                              hipStream_t stream) {
    (void)in_sizes; (void)n_in; (void)out_size;
    const float* x    = (const float*)d_in[0];
    const float* temb = (const float*)d_in[1];
    const float* semb = (const float*)d_in[2];
    const float* adj  = (const float*)d_in[3];
    const float* Wg   = (const float*)d_in[4];
    const float* bias = (const float*)d_in[5];
    float* out = (float*)d_out;

    if (ws_size >= (size_t)WS_NEED) {
        bf16x8* Apk = (bf16x8*)((char*)d_ws + WS_A_OFF);
        u32x4*  Bpk = (u32x4*)((char*)d_ws + WS_B_OFF);
        u32x4*  Wpk = (u32x4*)((char*)d_ws + WS_W_OFF);

        prep_a<<<dim3(1536), 256, 0, stream>>>(x, temb, semb, Apk);
        prep_bw<<<dim3(1188), 256, 0, stream>>>(adj, Wg, Bpk, Wpk);

        stsgcl_main<<<dim3(1120), 256, 0, stream>>>(Apk, (const bf16x8*)Bpk, (const bf16x8*)Wpk, bias, out);
    } else {
        dim3 grid(14, B_ * TTW);
        stsgcl_fused<<<grid, 256, 0, stream>>>(x, temb, semb, adj, Wg, bias, out);
    }
}

// Round 8
// 350.189 us; speedup vs baseline: 1.3465x; 1.0878x over previous
//
#include <hip/hip_runtime.h>
#include <math.h>

#define B_   32
#define C_   64
#define T_   12
#define NV   883
#define TTW  10          // T-2 output time steps
#define K3   2649        // 3*NV
#define KSEG 28          // k-tiles per 883-segment (28*32=896, zero-padded)

typedef __attribute__((ext_vector_type(8))) short bf16x8;   // 8 bf16 = 4 VGPRs (MFMA A/B frag)
typedef __attribute__((ext_vector_type(4))) float f32x4;    // MFMA C/D frag
typedef __attribute__((ext_vector_type(4))) unsigned int u32x4;

// ---- workspace layout (all 16B aligned) ----
// Apk: [b*12+s][kt<28][af<4][lane<64] x 16B  = 384*28*4*1024 = 44,040,192
// Bpk: [bx2<14][seg<3][kt<28][bfi<4][lane]   = 14*3*28*4*1024 = 4,816,896
// Wpk: [(gi*8+df)*2+kc][lane]                = 48*1024 = 49,152
#define WS_A_OFF   0ull
#define WS_A_BYTES 44040192ull
#define WS_B_OFF   (WS_A_OFF + WS_A_BYTES)
#define WS_B_BYTES 4816896ull
#define WS_W_OFF   (WS_B_OFF + WS_B_BYTES)
#define WS_W_BYTES 49152ull
#define WS_NEED    (WS_W_OFF + WS_W_BYTES)   // 48,906,240

__device__ __forceinline__ unsigned short f2bf(float f) {
    union { float f; unsigned int u; } v; v.f = f;
    unsigned int r = v.u + 0x7fffu + ((v.u >> 16) & 1u);   // RNE
    return (unsigned short)(r >> 16);
}

// async global->LDS, 16B per lane. LDS dest is wave-uniform base + lane*16
// (HW-applied); global src is per-lane. Counted by vmcnt.
__device__ __forceinline__ void gload_lds16(const void* g, void* l) {
    __builtin_amdgcn_global_load_lds(
        (const __attribute__((address_space(1))) void*)g,
        (__attribute__((address_space(3))) void*)l,
        16, 0, 0);
}

// ---------------- fused prep kernel ----------------
// blocks 0..1535       : A-pack v2 (R7 structure — deep independent-load MLP)
// blocks 1536..2711    : B-pack (adj middle rows -> per-segment B frags)
// blocks 2712..2723    : W-pack
// Single dispatch: the three packs are independent; fusing removes launch
// gaps and lets B/W blocks fill CUs alongside A blocks.
__global__ __launch_bounds__(256) void prep_all(const float* __restrict__ x,
                                                const float* __restrict__ temb,
                                                const float* __restrict__ semb,
                                                const float* __restrict__ adj,
                                                const float* __restrict__ W,
                                                bf16x8* __restrict__ Apk,
                                                u32x4* __restrict__ Bpk,
                                                u32x4* __restrict__ Wpk) {
    __shared__ short hs[16 * 904];          // 28,928 B (A-pack only; pad 904)
    const int tid = threadIdx.x;

    if (blockIdx.x < 1536) {
        // ---- A-pack: h = x + temb + semb, bf16, MFMA A-frag order ----
        const int bs  = blockIdx.x >> 2;        // 0..383 = b*12 + s
        const int ch2 = blockIdx.x & 3;
        const int ch  = ch2 >> 1, a2 = ch2 & 1;
        const int af  = ch * 2 + a2;            // 0..3
        const int b   = bs / 12, s = bs - b * 12;

        const int cl = tid >> 4;                // 0..15 (row)
        const int kq = tid & 15;                // 0..15
        const int c  = ch * 32 + a2 * 16 + cl;
        const float te = temb[c * T_ + s];
        const float* xr = x + ((size_t)(b * C_ + c) * T_ + s) * NV;
        const float* sr = semb + (size_t)c * NV;
        short* hrow = &hs[cl * 904];
#pragma unroll 14
        for (int i = 0; i < 56; ++i) {
            const int k = kq + 16 * i;          // 0..895
            float v = 0.f;
            if (k < NV) v = xr[k] + te + sr[k];
            hrow[k] = (short)f2bf(v);
        }
        __syncthreads();
        // frags for this af: kt<28 x lane<64 = 1792; 7 per thread
        for (int i = tid; i < 1792; i += 256) {
            const int lane = i & 63;
            const int kt = i >> 6;
            const int k0 = kt * 32 + (lane >> 4) * 8;
            const bf16x8 vv = *(const bf16x8*)&hs[(lane & 15) * 904 + k0];
            Apk[(size_t)((bs * KSEG + kt) * 4 + af) * 64 + lane] = vv;
        }
        return;
    }

    const int l = tid & 63;
    if (blockIdx.x < 1536 + 1176) {
        // ---- B-pack ----
        const int chunk = (blockIdx.x - 1536) * 4 + (tid >> 6);   // 0..4703
        const int bfi = chunk & 3;
        int tmp = chunk >> 2;
        const int kt = tmp % KSEG;  tmp /= KSEG;
        const int seg = tmp % 3;
        const int bx2 = tmp / 3;                                  // 0..13
        const int m16 = bx2 * 4 + bfi;                            // 0..55
        const int row = NV + m16 * 16 + (l & 15);                 // <= 1778 < 2649
        const float* src = adj + (size_t)row * K3 + seg * NV;
        const int k0 = kt * 32 + (l >> 4) * 8;
        unsigned short u[8];
#pragma unroll
        for (int i = 0; i < 8; ++i) {
            const int kk = k0 + i;
            u[i] = (kk < NV) ? f2bf(src[kk]) : (unsigned short)0;
        }
        u32x4 pk;
        pk[0] = u[0] | ((unsigned)u[1] << 16);
        pk[1] = u[2] | ((unsigned)u[3] << 16);
        pk[2] = u[4] | ((unsigned)u[5] << 16);
        pk[3] = u[6] | ((unsigned)u[7] << 16);
        Bpk[(size_t)chunk * 64 + l] = pk;
    } else {
        // ---- W-pack ----
        const int chunk = (blockIdx.x - 1536 - 1176) * 4 + (tid >> 6);   // 0..47
        const int c24 = chunk >> 1;
        const int kc  = chunk & 1;
        const int gi  = c24 >> 3;
        const int df  = c24 & 7;
        const int d   = 16 * df + (l & 15);
        const int c0  = kc * 32 + (l >> 4) * 8;
        const float* src = W + (size_t)gi * C_ * 128 + d;
        unsigned short u[8];
#pragma unroll
        for (int i = 0; i < 8; ++i) u[i] = f2bf(src[(size_t)(c0 + i) * 128]);
        u32x4 pk;
        pk[0] = u[0] | ((unsigned)u[1] << 16);
        pk[1] = u[2] | ((unsigned)u[3] << 16);
        pk[2] = u[4] | ((unsigned)u[5] << 16);
        pk[3] = u[6] | ((unsigned)u[7] << 16);
        Wpk[(size_t)chunk * 64 + l] = pk;
    }
}

// ---------------- main kernel: counted-vmcnt ring-staged GEMM + fused GLU epilogue ----------------
// REVERTED TO ROUND-4 STRUCTURE (measured 170 µs — best of 6 structural
// variants; R5 8-wave=198, R6 split-path=194, R7 barrier-free=214 all lost).
// block = 128 m x 2 bt; wave = 64 m x 1 bt; acc = 4 af x 4 bf f32x4.
// 1-D grid of 1120 blocks, XCD-swizzled (round-2: FETCH 424->92 MB).
// Stage 1: 3-buffer LDS ring with COUNTED vmcnt (T4) — per phase:
//   s_waitcnt vmcnt(4)  (buf[st] ready; buf[st+1]'s 4 loads stay in flight)
//   s_barrier           (all waves' buf[st] writes visible; all done reading buf[st+2])
//   issue buf[st+2]     (after barrier -> WAR-safe vs phase st-1 readers)
//   ds_read buf[st], 16 MFMA under setprio(1) (T5)
// Never drains vmcnt to 0 in the main loop. Tail phase peeled with vmcnt(0).
__global__ __launch_bounds__(256, 3) void stsgcl_main(
    const bf16x8* __restrict__ Apk,
    const bf16x8* __restrict__ Bpk,
    const bf16x8* __restrict__ Wpk,
    const float* __restrict__ bias,
    float* __restrict__ out)
{
    __shared__ union {
        short stage[3][16][512];   // 3 ring bufs x 16 frags x 1 KB = 49,152 B
        short gs[4][64 * 72];      // per-wave 64m x 72c bf16 = 36,864 B
    } sm;

    const int tid  = threadIdx.x;
    const int lane = tid & 63;
    const int w    = tid >> 6;
    const int q    = lane >> 4;
    const int lo   = lane & 15;
    const int btl  = w >> 1;                // bt within pair
    const int mh   = w & 1;                 // 64-m half

    // XCD-aware decode (1120 = 8 XCDs * 20 pair-groups * 7 m-blocks)
    const int flat = blockIdx.x;
    const int xcd  = flat & 7;
    const int idx  = flat >> 3;             // 0..139
    const int grp  = idx / 7;               // 0..19
    const int bx   = idx - grp * 7;         // 0..6
    const int pair = xcd * 20 + grp;        // 0..159
    const int bt   = pair * 2 + btl;        // 0..319
    const int bb   = bt / TTW;
    const int t    = bt - bb * TTW;

    f32x4 acc[4][4];
#pragma unroll
    for (int i = 0; i < 4; ++i)
#pragma unroll
        for (int j = 0; j < 4; ++j)
#pragma unroll
            for (int r = 0; r < 4; ++r) acc[i][j][r] = 0.f;

    // ---- stage 1: 84 k-steps (3 segs x 28 kt contiguous), 3-buf counted ring ----
    // per-wave staging source: w0/w1 stage A(bt0/bt1), w2/w3 stage B(mh0/mh1)
    const char* src_base;
    if (w < 2) {
        const int btw = pair * 2 + w;
        const int bbw = btw / TTW, tw = btw - bbw * TTW;
        src_base = (const char*)(Apk + (size_t)((bbw * T_ + tw) * KSEG) * 256);
    } else {
        const int bx2w = bx * 2 + (w - 2);
        src_base = (const char*)(Bpk + (size_t)(bx2w * 3 * KSEG) * 256);
    }
    src_base += (size_t)lane * 16;
    // step stride = 4 frags * 1024 B = 4096 B; frag stride = 1024 B

    // prologue: stage steps 0,1 into bufs 0,1 (8 loads outstanding)
#pragma unroll
    for (int f = 0; f < 4; ++f)
        gload_lds16(src_base + f * 1024, &sm.stage[0][4 * w + f][0]);
#pragma unroll
    for (int f = 0; f < 4; ++f)
        gload_lds16(src_base + 4096 + f * 1024, &sm.stage[1][4 * w + f][0]);
    const char* sp = src_base + 2 * 4096;   // src of next step to stage

    const int ga = btl * 4;                 // A frag group for this wave
    const int gb = 8 + mh * 4;              // B frag group

    int rb = 0;                             // read buffer = st % 3
#pragma unroll 1
    for (int st = 0; st < 83; ++st) {
        // buf[st] ready when <=4 outstanding (only buf[st+1]'s remain)
        asm volatile("s_waitcnt vmcnt(4)\n\ts_barrier" ::: "memory");
        if (st < 82) {
            int wb = rb + 2; if (wb >= 3) wb -= 3;
            short* dst = &sm.stage[wb][4 * w][0];
#pragma unroll
            for (int f = 0; f < 4; ++f)
                gload_lds16(sp + f * 1024, dst + f * 512);
            sp += 4096;
        }
        bf16x8 av[4], bv[4];
#pragma unroll
        for (int i = 0; i < 4; ++i) av[i] = *(const bf16x8*)&sm.stage[rb][ga + i][lane << 3];
#pragma unroll
        for (int j = 0; j < 4; ++j) bv[j] = *(const bf16x8*)&sm.stage[rb][gb + j][lane << 3];
        __builtin_amdgcn_s_setprio(1);
#pragma unroll
        for (int i = 0; i < 4; ++i)
#pragma unroll
            for (int j = 0; j < 4; ++j)
                acc[i][j] = __builtin_amdgcn_mfma_f32_16x16x32_bf16(av[i], bv[j], acc[i][j], 0, 0, 0);
        __builtin_amdgcn_s_setprio(0);
        if (++rb == 3) rb = 0;
    }
    // peeled final phase (st=83): fully drain (no loads behind it)
    {
        asm volatile("s_waitcnt vmcnt(0)\n\ts_barrier" ::: "memory");
        bf16x8 av[4], bv[4];
#pragma unroll
        for (int i = 0; i < 4; ++i) av[i] = *(const bf16x8*)&sm.stage[rb][ga + i][lane << 3];
#pragma unroll
        for (int j = 0; j < 4; ++j) bv[j] = *(const bf16x8*)&sm.stage[rb][gb + j][lane << 3];
        __builtin_amdgcn_s_setprio(1);
#pragma unroll
        for (int i = 0; i < 4; ++i)
#pragma unroll
            for (int j = 0; j < 4; ++j)
                acc[i][j] = __builtin_amdgcn_mfma_f32_16x16x32_bf16(av[i], bv[j], acc[i][j], 0, 0, 0);
        __builtin_amdgcn_s_setprio(0);
    }
    __syncthreads();   // all waves done with stage bufs before gs overwrite

    // ---- transpose g (D-layout: c rows x m cols) -> gs[w][m][c] bf16 ----
    short* gw = &sm.gs[w][0];
#pragma unroll
    for (int af = 0; af < 4; ++af)
#pragma unroll
        for (int bf = 0; bf < 4; ++bf) {
            uint2 pk;
            pk.x = (unsigned)f2bf(acc[af][bf][0]) | ((unsigned)f2bf(acc[af][bf][1]) << 16);
            pk.y = (unsigned)f2bf(acc[af][bf][2]) | ((unsigned)f2bf(acc[af][bf][3]) << 16);
            *(uint2*)&gw[(16 * bf + lo) * 72 + 16 * af + 4 * q] = pk;   // c = 16af+4q+r, m = 16bf+lo
        }
    // same-wave RAW through LDS: compiler orders via lgkmcnt

    // ---- stage 2 per m-group: z = g^T . W[gi], GLU, max over branches, store ----
#pragma unroll 1
    for (int mg = 0; mg < 4; ++mg) {
        const short* arow = &gw[(16 * mg + lo) * 72];
        const bf16x8 a2k0 = *(const bf16x8*)&arow[q * 8];        // c = 0..31
        const bf16x8 a2k1 = *(const bf16x8*)&arow[32 + q * 8];   // c = 32..63

        float om[4][4];
#pragma unroll
        for (int i = 0; i < 4; ++i)
#pragma unroll
            for (int r = 0; r < 4; ++r) om[i][r] = -3.4e38f;

#pragma unroll 1
        for (int gi = 0; gi < 3; ++gi) {
            f32x4 z[8];
#pragma unroll
            for (int i = 0; i < 8; ++i)
#pragma unroll
                for (int r = 0; r < 4; ++r) z[i][r] = 0.f;
#pragma unroll
            for (int df = 0; df < 8; ++df) {
                z[df] = __builtin_amdgcn_mfma_f32_16x16x32_bf16(
                    a2k0, Wpk[(size_t)(((gi * 8 + df) * 2 + 0)) * 64 + lane], z[df], 0, 0, 0);
                z[df] = __builtin_amdgcn_mfma_f32_16x16x32_bf16(
                    a2k1, Wpk[(size_t)(((gi * 8 + df) * 2 + 1)) * 64 + lane], z[df], 0, 0, 0);
            }
#pragma unroll
            for (int df = 0; df < 4; ++df) {
                const float b1 = bias[gi * 128 + 16 * df + lo];
                const float b2 = bias[gi * 128 + 64 + 16 * df + lo];
#pragma unroll
                for (int r = 0; r < 4; ++r) {
                    const float z1 = z[df][r] + b1;
                    const float z2 = z[df + 4][r] + b2;
                    const float sg = 1.0f / (1.0f + __expf(-z2));
                    om[df][r] = fmaxf(om[df][r], z1 * sg);
                }
            }
        }

        const int m16g = bx * 8 + mh * 4 + mg;      // 0..55
        const int mvb  = m16g * 16 + 4 * q;         // D row = 4q + r
#pragma unroll
        for (int df = 0; df < 4; ++df) {
            const int cout = 16 * df + lo;
            float* orow = out + ((size_t)(bb * C_ + cout) * TTW + t) * NV + mvb;
#pragma unroll
            for (int r = 0; r < 4; ++r) {
                if (mvb + r < NV) orow[r] = om[df][r];
            }
        }
    }
}

// ---------------- fallback: round-1 verified fp32 kernel (tiny ws) ----------------
__global__ __launch_bounds__(256) void stsgcl_fused(
    const float* __restrict__ x, const float* __restrict__ temb,
    const float* __restrict__ semb, const float* __restrict__ adj,
    const float* __restrict__ Wg, const float* __restrict__ bias,
    float* __restrict__ out)
{
    __shared__ union {
        struct { float As[32][64]; float Bs[32][64]; } s1;
        float Ws[64][128];
    } sm;
    __shared__ float Gsf[64][64];

    const int tid = threadIdx.x;
    const int bt = blockIdx.y;
    const int bb = bt / TTW;
    const int t  = bt % TTW;
    const int m0 = blockIdx.x * 64;
    const int tr = tid >> 4, tc = tid & 15;
    const int lrow = tid >> 2;
    const int kq = (tid & 3) * 8;

    const float* xrow = x + ((size_t)(bb * C_ + lrow) * T_ + t) * NV;
    const float* brow = adj + (size_t)(NV + m0 + lrow) * K3;
    const float* srow = semb + (size_t)lrow * NV;
    const float te0 = temb[lrow * T_ + t], te1 = temb[lrow * T_ + t + 1], te2 = temb[lrow * T_ + t + 2];

    float acc[4][4];
#pragma unroll
    for (int i = 0; i < 4; ++i)
#pragma unroll
        for (int j = 0; j < 4; ++j) acc[i][j] = 0.f;

    for (int kt = 0; kt < (K3 + 31) / 32; ++kt) {
        const int kg0 = kt * 32 + kq;
        {
            int tt, n;
            if (kg0 >= 2 * NV) { tt = 2; n = kg0 - 2 * NV; }
            else if (kg0 >= NV) { tt = 1; n = kg0 - NV; }
            else { tt = 0; n = kg0; }
#pragma unroll
            for (int i = 0; i < 8; ++i) {
                float v = 0.f;
                if (kg0 + i < K3) {
                    const float tev = (tt == 0) ? te0 : ((tt == 1) ? te1 : te2);
                    v = xrow[tt * NV + n] + tev + srow[n];
                }
                sm.s1.As[kq + i][lrow] = v;
                if (++n == NV) { n = 0; ++tt; }
            }
        }
#pragma unroll
        for (int i = 0; i < 8; ++i) sm.s1.Bs[kq + i][lrow] = brow[kg0 + i];
        __syncthreads();
#pragma unroll
        for (int kk = 0; kk < 32; ++kk) {
            const float4 a = *(const float4*)&sm.s1.As[kk][tr * 4];
            const float4 bv = *(const float4*)&sm.s1.Bs[kk][tc * 4];
            const float av[4] = {a.x, a.y, a.z, a.w};
            const float bw[4] = {bv.x, bv.y, bv.z, bv.w};
#pragma unroll
            for (int i = 0; i < 4; ++i)
#pragma unroll
                for (int j = 0; j < 4; ++j) acc[i][j] += av[i] * bw[j];
        }
        __syncthreads();
    }
#pragma unroll
    for (int i = 0; i < 4; ++i)
#pragma unroll
        for (int j = 0; j < 4; ++j) Gsf[tr * 4 + i][tc * 4 + j] = acc[i][j];

    const int pg = tid & 15, cg = tid >> 4;
    float omax[4][4];
#pragma unroll
    for (int i = 0; i < 4; ++i)
#pragma unroll
        for (int j = 0; j < 4; ++j) omax[i][j] = -3.4e38f;

    for (int gi = 0; gi < 3; ++gi) {
        __syncthreads();
        {
            const float4* wsrc = (const float4*)(Wg + (size_t)gi * C_ * 128);
            float4* wdst = (float4*)&sm.Ws[0][0];
#pragma unroll
            for (int i = 0; i < 8; ++i) wdst[tid + i * 256] = wsrc[tid + i * 256];
        }
        __syncthreads();
        float z1[4][4], z2[4][4];
#pragma unroll
        for (int j = 0; j < 4; ++j) {
            const float b1 = bias[gi * 128 + cg * 4 + j];
            const float b2 = bias[gi * 128 + 64 + cg * 4 + j];
#pragma unroll
            for (int i = 0; i < 4; ++i) { z1[i][j] = b1; z2[i][j] = b2; }
        }
#pragma unroll 8
        for (int cc = 0; cc < 64; ++cc) {
            const float4 gv = *(const float4*)&Gsf[cc][pg * 4];
            const float4 w1 = *(const float4*)&sm.Ws[cc][cg * 4];
            const float4 w2 = *(const float4*)&sm.Ws[cc][64 + cg * 4];
            const float gva[4] = {gv.x, gv.y, gv.z, gv.w};
            const float w1a[4] = {w1.x, w1.y, w1.z, w1.w};
            const float w2a[4] = {w2.x, w2.y, w2.z, w2.w};
#pragma unroll
            for (int i = 0; i < 4; ++i)
#pragma unroll
                for (int j = 0; j < 4; ++j) { z1[i][j] += gva[i] * w1a[j]; z2[i][j] += gva[i] * w2a[j]; }
        }
#pragma unroll
        for (int i = 0; i < 4; ++i)
#pragma unroll
            for (int j = 0; j < 4; ++j) {
                const float s = 1.0f / (1.0f + __expf(-z2[i][j]));
                omax[i][j] = fmaxf(omax[i][j], z1[i][j] * s);
            }
    }
    const int mmb = m0 + pg * 4;
#pragma unroll
    for (int j = 0; j < 4; ++j) {
        const int co = cg * 4 + j;
        float* orow = out + ((size_t)(bb * C_ + co) * TTW + t) * NV;
#pragma unroll
        for (int i = 0; i < 4; ++i) {
            const int mm = mmb + i;
            if (mm < NV) orow[mm] = omax[i][j];
        }
    }
}

extern "C" void kernel_launch(void* const* d_in, const int* in_sizes, int n_in,
                              void* d_out, int out_size, void* d_ws, size_t ws_size,
                              hipStream_t stream) {
    (void)in_sizes; (void)n_in; (void)out_size;
    const float* x    = (const float*)d_in[0];
    const float* temb = (const float*)d_in[1];
    const float* semb = (const float*)d_in[2];
    const float* adj  = (const float*)d_in[3];
    const float* Wg   = (const float*)d_in[4];
    const float* bias = (const float*)d_in[5];
    float* out = (float*)d_out;

    if (ws_size >= (size_t)WS_NEED) {
        bf16x8* Apk = (bf16x8*)((char*)d_ws + WS_A_OFF);
        u32x4*  Bpk = (u32x4*)((char*)d_ws + WS_B_OFF);
        u32x4*  Wpk = (u32x4*)((char*)d_ws + WS_W_OFF);

        prep_all<<<dim3(2724), 256, 0, stream>>>(x, temb, semb, adj, Wg,
                                                 Apk, Bpk, Wpk);

        stsgcl_main<<<dim3(1120), 256, 0, stream>>>(Apk, (const bf16x8*)Bpk, (const bf16x8*)Wpk, bias, out);
    } else {
        dim3 grid(14, B_ * TTW);
        stsgcl_fused<<<grid, 256, 0, stream>>>(x, temb, semb, adj, Wg, bias, out);
    }
}